// Round 9
// baseline (814.270 us; speedup 1.0000x reference)
//
#include <hip/hip_runtime.h>
#include <math.h>

#define T_ 16
#define B_ 512
#define N_ 8192
#define G_ 39
#define ENC_ 128
#define TH_ 64
#define MROWS 8704          // B_ + N_
#define GATE 512            // 4*ENC_
#define KCAT 192            // TH_ + ENC_
#define SCALE_ 0.08838834764831845f
#define LNEPS 1e-5f
#define NBLK3 136           // MROWS/64 blocks of 4 waves x 16 rows

typedef short bf16x8 __attribute__((ext_vector_type(8)));
typedef float f32x4  __attribute__((ext_vector_type(4)));

__device__ __forceinline__ float sigm(float x){ return 1.0f/(1.0f+expf(-x)); }
__device__ __forceinline__ float rcpf(float x){ return __builtin_amdgcn_rcpf(x); }
__device__ __forceinline__ float sigm_f(float x){ return rcpf(1.0f + __expf(-x)); }
__device__ __forceinline__ float tanh_f(float x){ return 1.0f - 2.0f*rcpf(__expf(2.0f*x) + 1.0f); }
__device__ __forceinline__ unsigned short f2bf(float f){
  unsigned int u = __float_as_uint(f);
  unsigned int r = u + 0x7FFFu + ((u>>16)&1u);
  return (unsigned short)(r>>16);
}
__device__ __forceinline__ float bf2f(unsigned short h){
  return __uint_as_float(((unsigned int)h)<<16);
}

// ================= prep: convert weights to bf16, build fused biases =================
__global__ __launch_bounds__(256) void k_prep(
    const float* __restrict__ Wih, const float* __restrict__ Whh,
    const float* __restrict__ bih, const float* __restrict__ bhh,
    const float* __restrict__ Wk,  const float* __restrict__ bk,
    const float* __restrict__ Wv,  const float* __restrict__ bv,
    const float* __restrict__ Wq,
    const float* __restrict__ Wqt, const float* __restrict__ bqt,
    const float* __restrict__ Wkt, const float* __restrict__ bkt,
    const float* __restrict__ Wvt, const float* __restrict__ bvt,
    const float* __restrict__ Wg1a, const float* __restrict__ bg1a,
    const float* __restrict__ Wg1g, const float* __restrict__ bg1g,
    const float* __restrict__ Wg2a, const float* __restrict__ bg2a,
    const float* __restrict__ Wg2g, const float* __restrict__ bg2g,
    unsigned short* __restrict__ WcatB, float* __restrict__ biasg,
    unsigned short* __restrict__ WkvB,  float* __restrict__ bkv,
    unsigned short* __restrict__ WqB,
    unsigned short* __restrict__ WqktB, float* __restrict__ bqkt,
    unsigned short* __restrict__ Wg1B,  float* __restrict__ bg1,
    unsigned short* __restrict__ Wg2B,  float* __restrict__ bg2)
{
  int i = blockIdx.x*256 + threadIdx.x;
  if (i < GATE*KCAT) {
    int n = i / KCAT, k = i % KCAT;
    WcatB[i] = f2bf((k < TH_) ? Wih[n*TH_ + k] : Whh[n*ENC_ + (k - TH_)]);
  }
  if (i < GATE) biasg[i] = bih[i] + bhh[i];
  if (i < 2*ENC_*ENC_) {
    int n = i >> 7, k = i & 127;
    WkvB[i] = f2bf((n < ENC_) ? Wk[n*ENC_ + k] : Wv[(n-ENC_)*ENC_ + k]);
    Wg1B[i] = f2bf((n < ENC_) ? Wg1a[n*ENC_ + k] : Wg1g[(n-ENC_)*ENC_ + k]);
    Wg2B[i] = f2bf((n < ENC_) ? Wg2a[n*ENC_ + k] : Wg2g[(n-ENC_)*ENC_ + k]);
  }
  if (i < 2*ENC_) {
    bkv[i] = (i < ENC_) ? bk[i] : bv[i-ENC_];
    bg1[i] = (i < ENC_) ? bg1a[i] : bg1g[i-ENC_];
    bg2[i] = (i < ENC_) ? bg2a[i] : bg2g[i-ENC_];
  }
  if (i < ENC_*ENC_) WqB[i] = f2bf(Wq[i]);
  if (i < 3*ENC_*ENC_) {
    int n = i >> 7, k = i & 127;
    float w = (n < ENC_) ? Wqt[n*ENC_ + k] : (n < 2*ENC_) ? Wkt[(n-ENC_)*ENC_ + k]
                                                          : Wvt[(n-2*ENC_)*ENC_ + k];
    WqktB[i] = f2bf(w);
  }
  if (i < 3*ENC_) bqkt[i] = (i < ENC_) ? bqt[i] : (i < 2*ENC_) ? bkt[i-ENC_] : bvt[i-2*ENC_];
}

// ================= mask width detect / count / fill (proven) =========================
__device__ __forceinline__ int cellval(const unsigned char* m, long cell, int w) {
  long byte = cell * 128L * w;
  if (w == 1) return m[byte] != 0;
  if (w == 2) return *(const unsigned short*)(m + byte) != 0;
  if (w == 4) return *(const unsigned int*)(m + byte) != 0;
  return *(const unsigned long long*)(m + byte) != 0ULL;
}
__device__ __forceinline__ int cellconsist(const unsigned char* m, long cell, int w) {
  long byte = cell * 128L * w;
  if (w == 1) { unsigned char v = m[byte];
    for (int j = 1; j < 8; ++j) if (m[byte + j] != v) return 0; return 1; }
  if (w == 2) { unsigned short v = *(const unsigned short*)(m + byte);
    for (int j = 1; j < 8; ++j) if (*(const unsigned short*)(m + byte + 2L*j) != v) return 0; return 1; }
  if (w == 4) { unsigned int v = *(const unsigned int*)(m + byte);
    for (int j = 1; j < 8; ++j) if (*(const unsigned int*)(m + byte + 4L*j) != v) return 0; return 1; }
  unsigned long long v = *(const unsigned long long*)(m + byte);
  for (int j = 1; j < 8; ++j) if (*(const unsigned long long*)(m + byte + 8L*j) != v) return 0; return 1;
}

__global__ void k_detect(const unsigned char* __restrict__ mask, int* __restrict__ wsel)
{
  __shared__ int bad;
  int tid = threadIdx.x;
  int chosen = 0;
  for (int w = 1; w <= 8 && !chosen; w <<= 1) {
    if (tid == 0) bad = 0;
    __syncthreads();
    int ok = 1;
    for (int c = tid; c < 512; c += 256) ok &= cellconsist(mask, c, w);
    if (!ok) bad = 1;
    __syncthreads();
    if (!bad) chosen = w;
    __syncthreads();
  }
  if (tid == 0) *wsel = chosen ? chosen : 1;
}

__global__ void k_count(const unsigned char* __restrict__ mask,
                        const int* __restrict__ wsel, int* __restrict__ bcnt)
{
  __shared__ int sc[256];
  int tid = threadIdx.x;
  long cell = (long)blockIdx.x*256 + tid;
  sc[tid] = cellval(mask, cell, *wsel);
  __syncthreads();
  for (int off = 128; off; off >>= 1) {
    if (tid < off) sc[tid] += sc[tid + off];
    __syncthreads();
  }
  if (tid == 0) bcnt[blockIdx.x] = sc[0];
}

__global__ void k_fill(const unsigned char* __restrict__ mask,
                       const int* __restrict__ wsel, const int* __restrict__ bcnt,
                       int* __restrict__ nidx)
{
  __shared__ int sc[256];
  int tid = threadIdx.x, blk = blockIdx.x;
  long cell = (long)blk*256 + tid;
  int on = cellval(mask, cell, *wsel);
  sc[tid] = on;
  __syncthreads();
  for (int off = 1; off < 256; off <<= 1) {
    int v = (tid >= off) ? sc[tid - off] : 0;
    __syncthreads();
    sc[tid] += v;
    __syncthreads();
  }
  int base = 0;
  for (int i = 0; i < blk; ++i) base += bcnt[i];
  nidx[cell] = on ? (base + sc[tid] - 1) : -1;
}

// ================= encode ALL t: elu(in5 @ W1^T + b1) -> XencB[t][m][64] bf16 =========
__global__ __launch_bounds__(256) void k_encode_all(
    const float* __restrict__ hist, const float* __restrict__ cls, const float* __restrict__ va,
    const float* __restrict__ nbrs, const float* __restrict__ nbrscls, const float* __restrict__ nbrsva,
    const float* __restrict__ W1, const float* __restrict__ b1,
    unsigned short* __restrict__ XencB)
{
  int i = blockIdx.x*256 + threadIdx.x;      // over MROWS*64
  int t = blockIdx.y;
  int o = i & 63, m = i >> 6;
  float in0, in1, in2, in3, in4;
  if (m < B_) {
    int r = t*B_ + m;
    in0 = hist[r*2]; in1 = hist[r*2+1]; in2 = cls[r]; in3 = va[r*2]; in4 = va[r*2+1];
  } else {
    int r = t*N_ + (m - B_);
    in0 = nbrs[r*2]; in1 = nbrs[r*2+1]; in2 = nbrscls[r]; in3 = nbrsva[r*2]; in4 = nbrsva[r*2+1];
  }
  const float* w = W1 + o*5;
  float s = b1[o] + in0*w[0] + in1*w[1] + in2*w[2] + in3*w[3] + in4*w[4];
  XencB[((long)t*MROWS + m)*64 + o] = f2bf((s > 0.0f) ? s : expm1f(s));
}

// ================= kernel A: wave-independent LSTM + projections =====================
struct AP {
  const unsigned short *Xenc, *Wcat, *Wkv, *Wq;
  const float *biasg, *bkv, *bq;
  float *hh;                 // (B,T,128) f32
  float *qbuf;               // (T,B,128) f32
  unsigned short *knvB;      // (tch,N,256) bf16
  unsigned short *Hsp;       // (MROWS,128) bf16 spill
  float *csp;                // (NBLK3*256*32) f32 spill of c-registers
  int c0, tch;
};

// 136 blocks x 4 waves; each wave owns 16 rows and the FULL recurrence for them.
// Zero __syncthreads: H lives in a wave-private LDS slice (stride 136 kills bank
// conflicts), c in registers, gate/proj weights streamed from L2.
__global__ __launch_bounds__(256, 1) void k_lstm(AP p)
{
  __shared__ unsigned short Hl[4][16*136 + 8];   // 4 x 4368 B, wave-private slices
  const int tid = threadIdx.x;
  const int w = tid >> 6, l = tid & 63;
  const int lr = l & 15, lk = (l >> 4) * 8, lq = (l >> 4) * 4;
  const int wgid = blockIdx.x*4 + w;
  const bool ish = (wgid < 32);                  // first 32 waves own hist rows
  const int bm16 = wgid * 16;
  unsigned short* Hw = &Hl[w][0];

  // ---- per-lane constants ----
  float bg[4][8];
  #pragma unroll
  for (int g = 0; g < 4; ++g)
    #pragma unroll
    for (int cx = 0; cx < 8; ++cx)
      bg[g][cx] = p.biasg[g*128 + cx*16 + lr];
  float bpro[16];
  if (!ish) {
    #pragma unroll
    for (int ni = 0; ni < 16; ++ni) bpro[ni] = p.bkv[ni*16 + lr];
  } else {
    #pragma unroll
    for (int ni = 0; ni < 8; ++ni) bpro[ni] = p.bq[ni*16 + lr];
  }

  // ---- restore / init state (wave-private, no barriers) ----
  float creg[8][4];
  if (p.c0 == 0) {
    for (int e = l; e < 16*136; e += 64) Hw[e] = 0;
    #pragma unroll
    for (int cx = 0; cx < 8; ++cx)
      #pragma unroll
      for (int q = 0; q < 4; ++q) creg[cx][q] = 0.0f;
  } else {
    for (int e = l; e < 16*128; e += 64) {
      int r = e >> 7, c = e & 127;
      Hw[r*136 + c] = p.Hsp[((long)bm16 + r)*128 + c];
    }
    #pragma unroll
    for (int cx = 0; cx < 8; ++cx)
      #pragma unroll
      for (int q = 0; q < 4; ++q)
        creg[cx][q] = p.csp[((long)blockIdx.x*256 + tid)*32 + cx*4 + q];
  }

  #pragma unroll 1
  for (int tl = 0; tl < p.tch; ++tl) {
    int t = p.c0 + tl;
    // ---- A-fragments: X (global, L3-hot) and old H (wave LDS) ----
    bf16x8 ax[2];
    #pragma unroll
    for (int ks = 0; ks < 2; ++ks)
      ax[ks] = *(const bf16x8*)(p.Xenc + ((long)t*MROWS + bm16 + lr)*64 + ks*32 + lk);
    bf16x8 ah[4];
    #pragma unroll
    for (int ks = 0; ks < 4; ++ks)
      ah[ks] = *(const bf16x8*)(Hw + lr*136 + ks*32 + lk);

    // ---- 8 channel-groups x 4 gates; cell update lane-local ----
    #pragma unroll
    for (int cx = 0; cx < 8; ++cx) {
      f32x4 ac[4] = {};
      #pragma unroll
      for (int ks = 0; ks < 6; ++ks) {
        bf16x8 a = (ks < 2) ? ax[ks] : ah[ks-2];
        #pragma unroll
        for (int g = 0; g < 4; ++g) {
          bf16x8 b = *(const bf16x8*)(p.Wcat + ((long)g*128 + cx*16 + lr)*KCAT + ks*32 + lk);
          ac[g] = __builtin_amdgcn_mfma_f32_16x16x32_bf16(a, b, ac[g], 0, 0, 0);
        }
      }
      #pragma unroll
      for (int q = 0; q < 4; ++q) {
        int row = lq + q;
        float gi = ac[0][q] + bg[0][cx];
        float gf = ac[1][q] + bg[1][cx];
        float gg = ac[2][q] + bg[2][cx];
        float go = ac[3][q] + bg[3][cx];
        float cc = sigm_f(gf)*creg[cx][q] + sigm_f(gi)*tanh_f(gg);
        creg[cx][q] = cc;
        float hv = sigm_f(go)*tanh_f(cc);
        Hw[row*136 + cx*16 + lr] = f2bf(hv);
        if (ish) p.hh[((long)(bm16 + row)*T_ + t)*128 + cx*16 + lr] = hv;
      }
    }
    // ---- projections from new H (in-wave LDS ordering guarantees visibility) ----
    bf16x8 an[4];
    #pragma unroll
    for (int ks = 0; ks < 4; ++ks)
      an[ks] = *(const bf16x8*)(Hw + lr*136 + ks*32 + lk);
    if (!ish) {
      unsigned short* kvb = p.knvB + ((long)tl*N_ + (bm16 - B_) + lq)*256 + lr;
      #pragma unroll
      for (int ni = 0; ni < 16; ++ni) {
        f32x4 a2 = {};
        #pragma unroll
        for (int ks = 0; ks < 4; ++ks) {
          bf16x8 b = *(const bf16x8*)(p.Wkv + ((long)ni*16 + lr)*128 + ks*32 + lk);
          a2 = __builtin_amdgcn_mfma_f32_16x16x32_bf16(an[ks], b, a2, 0, 0, 0);
        }
        #pragma unroll
        for (int q = 0; q < 4; ++q)
          kvb[q*256 + ni*16] = f2bf(a2[q] + bpro[ni]);
      }
    } else {
      float* qb = p.qbuf + ((long)t*B_ + bm16 + lq)*128 + lr;
      #pragma unroll
      for (int ni = 0; ni < 8; ++ni) {
        f32x4 a2 = {};
        #pragma unroll
        for (int ks = 0; ks < 4; ++ks) {
          bf16x8 b = *(const bf16x8*)(p.Wq + ((long)ni*16 + lr)*128 + ks*32 + lk);
          a2 = __builtin_amdgcn_mfma_f32_16x16x32_bf16(an[ks], b, a2, 0, 0, 0);
        }
        #pragma unroll
        for (int q = 0; q < 4; ++q)
          qb[q*128 + ni*16] = a2[q] + bpro[ni];
      }
    }
  }
  // ---- spill state for next chunk ----
  for (int e = l; e < 16*128; e += 64) {
    int r = e >> 7, c = e & 127;
    p.Hsp[((long)bm16 + r)*128 + c] = Hw[r*136 + c];
  }
  #pragma unroll
  for (int cx = 0; cx < 8; ++cx)
    #pragma unroll
    for (int q = 0; q < 4; ++q)
      p.csp[((long)blockIdx.x*256 + tid)*32 + cx*4 + q] = creg[cx][q];
}

// ================= kernel B: spatial attention, one wave per (b, t) ==================
__global__ __launch_bounds__(256) void k_attn_sp(
    int c0, int ltch,
    const float* __restrict__ qbuf, const unsigned short* __restrict__ knvB,
    const float* __restrict__ bk, const float* __restrict__ bv,
    const int* __restrict__ nidx, unsigned short* __restrict__ spaB)
{
  int tid = threadIdx.x;
  int w = tid >> 6, l = tid & 63;
  __shared__ int sn[4][G_];
  __shared__ float aw[4][4][40];
  int gwid = blockIdx.x*4 + w;
  int b = gwid >> ltch;
  int tl = gwid & ((1 << ltch) - 1);
  int t = c0 + tl;
  if (l < G_) sn[w][l] = nidx[b*G_ + l];
  __syncthreads();
  float qA = qbuf[((long)t*B_ + b)*128 + l];
  float qB = qbuf[((long)t*B_ + b)*128 + 64 + l];
  for (int g = 0; g < G_; ++g) {
    int ni = sn[w][g];
    const unsigned short* kr = knvB + ((long)tl*N_ + ni)*256;
    float kA = (ni >= 0) ? bf2f(kr[l])      : bk[l];
    float kB = (ni >= 0) ? bf2f(kr[64 + l]) : bk[64 + l];
    float pA = qA*kA, pB = qB*kB;
    pA += __shfl_xor(pA, 16); pA += __shfl_xor(pA, 8); pA += __shfl_xor(pA, 4);
    pA += __shfl_xor(pA, 2);  pA += __shfl_xor(pA, 1);
    pB += __shfl_xor(pB, 16); pB += __shfl_xor(pB, 8); pB += __shfl_xor(pB, 4);
    pB += __shfl_xor(pB, 2);  pB += __shfl_xor(pB, 1);
    if ((l & 31) == 0) {
      int hb = l >> 5;
      aw[w][hb][g]     = pA * SCALE_;
      aw[w][2+hb][g]   = pB * SCALE_;
    }
  }
  __syncthreads();
  int hA = l >> 5, hB = 2 + (l >> 5);
  float mxA = -1e30f, mxB = -1e30f;
  for (int g = 0; g < G_; ++g) {
    mxA = fmaxf(mxA, aw[w][hA][g]);
    mxB = fmaxf(mxB, aw[w][hB][g]);
  }
  float sA = 0.f, sB = 0.f, oA = 0.f, oB = 0.f;
  for (int g = 0; g < G_; ++g) {
    int ni = sn[w][g];
    const unsigned short* vr = knvB + ((long)tl*N_ + ni)*256 + 128;
    float vA = (ni >= 0) ? bf2f(vr[l])      : bv[l];
    float vB = (ni >= 0) ? bf2f(vr[64 + l]) : bv[64 + l];
    float eA = expf(aw[w][hA][g] - mxA);
    float eB = expf(aw[w][hB][g] - mxB);
    sA += eA; sB += eB; oA += eA*vA; oB += eB*vB;
  }
  spaB[((long)b*T_ + t)*128 + l]      = f2bf(oA / sA);
  spaB[((long)b*T_ + t)*128 + 64 + l] = f2bf(oB / sB);
}

// ================= bf16 MFMA GEMM: C f32 out =========================================
__global__ __launch_bounds__(256) void k_gemm_bf16(
    const unsigned short* __restrict__ A, int lda,
    const unsigned short* __restrict__ W, int ldw,
    const float* __restrict__ bias,
    float* __restrict__ C, int ldc, int K)
{
  int tid = threadIdx.x;
  int w = tid >> 6, l = tid & 63;
  int lr = l & 15, lk = (l >> 4) * 8, lq = (l >> 4) * 4;
  int bm = blockIdx.x * 64;
  int bn = blockIdx.y * 128 + w * 32;
  f32x4 acc[4][2] = {};
  for (int k0 = 0; k0 < K; k0 += 32) {
    bf16x8 a[4], b[2];
    #pragma unroll
    for (int mi = 0; mi < 4; ++mi)
      a[mi] = *(const bf16x8*)(A + (long)(bm + mi*16 + lr)*lda + k0 + lk);
    #pragma unroll
    for (int ni = 0; ni < 2; ++ni)
      b[ni] = *(const bf16x8*)(W + (long)(bn + ni*16 + lr)*ldw + k0 + lk);
    #pragma unroll
    for (int mi = 0; mi < 4; ++mi)
      #pragma unroll
      for (int ni = 0; ni < 2; ++ni)
        acc[mi][ni] = __builtin_amdgcn_mfma_f32_16x16x32_bf16(a[mi], b[ni], acc[mi][ni], 0, 0, 0);
  }
  #pragma unroll
  for (int mi = 0; mi < 4; ++mi)
    #pragma unroll
    for (int ni = 0; ni < 2; ++ni) {
      int col = bn + ni*16 + lr;
      float bb = bias[col];
      #pragma unroll
      for (int q = 0; q < 4; ++q)
        C[(long)(bm + mi*16 + lq + q)*ldc + col] = acc[mi][ni][q] + bb;
    }
}

// same but bf16 output (for qkt)
__global__ __launch_bounds__(256) void k_gemm_bf16o(
    const unsigned short* __restrict__ A, int lda,
    const unsigned short* __restrict__ W, int ldw,
    const float* __restrict__ bias,
    unsigned short* __restrict__ C, int ldc, int K)
{
  int tid = threadIdx.x;
  int w = tid >> 6, l = tid & 63;
  int lr = l & 15, lk = (l >> 4) * 8, lq = (l >> 4) * 4;
  int bm = blockIdx.x * 64;
  int bn = blockIdx.y * 128 + w * 32;
  f32x4 acc[4][2] = {};
  for (int k0 = 0; k0 < K; k0 += 32) {
    bf16x8 a[4], b[2];
    #pragma unroll
    for (int mi = 0; mi < 4; ++mi)
      a[mi] = *(const bf16x8*)(A + (long)(bm + mi*16 + lr)*lda + k0 + lk);
    #pragma unroll
    for (int ni = 0; ni < 2; ++ni)
      b[ni] = *(const bf16x8*)(W + (long)(bn + ni*16 + lr)*ldw + k0 + lk);
    #pragma unroll
    for (int mi = 0; mi < 4; ++mi)
      #pragma unroll
      for (int ni = 0; ni < 2; ++ni)
        acc[mi][ni] = __builtin_amdgcn_mfma_f32_16x16x32_bf16(a[mi], b[ni], acc[mi][ni], 0, 0, 0);
  }
  #pragma unroll
  for (int mi = 0; mi < 4; ++mi)
    #pragma unroll
    for (int ni = 0; ni < 2; ++ni) {
      int col = bn + ni*16 + lr;
      float bb = bias[col];
      #pragma unroll
      for (int q = 0; q < 4; ++q)
        C[(long)(bm + mi*16 + lq + q)*ldc + col] = f2bf(acc[mi][ni][q] + bb);
    }
}

// ================= fused glu + residual add + layernorm ==============================
__global__ __launch_bounds__(256) void k_glu_addln(
    const float* __restrict__ t12, const float* __restrict__ res,
    const float* __restrict__ lg, const float* __restrict__ lb,
    float* __restrict__ sum_out, unsigned short* __restrict__ ln_bf16,
    float* __restrict__ ln_f32)
{
  int gtid = blockIdx.x*256 + threadIdx.x;
  int r = gtid >> 6;
  int l = threadIdx.x & 63;
  if (r >= B_*T_) return;
  long b4 = (long)r*256, b2 = (long)r*128;
  float xA = res[b2 + l]      + t12[b4 + l]      * sigm(t12[b4 + 128 + l]);
  float xB = res[b2 + 64 + l] + t12[b4 + 64 + l] * sigm(t12[b4 + 192 + l]);
  if (sum_out) { sum_out[b2 + l] = xA; sum_out[b2 + 64 + l] = xB; }
  float s = xA + xB, s2 = xA*xA + xB*xB;
  #pragma unroll
  for (int off = 32; off; off >>= 1) { s += __shfl_xor(s, off); s2 += __shfl_xor(s2, off); }
  float mean = s * (1.0f/128.0f);
  float var  = s2 * (1.0f/128.0f) - mean*mean;
  float inv  = rsqrtf(var + LNEPS);
  float oA = (xA - mean)*inv*lg[l]      + lb[l];
  float oB = (xB - mean)*inv*lg[64 + l] + lb[64 + l];
  if (ln_bf16) { ln_bf16[b2 + l] = f2bf(oA); ln_bf16[b2 + 64 + l] = f2bf(oB); }
  if (ln_f32)  { ln_f32[b2 + l] = oA;        ln_f32[b2 + 64 + l] = oB; }
}

// ================= temporal attention (bf16 qkt input) ===============================
__global__ __launch_bounds__(128) void k_attn_t(
    const unsigned short* __restrict__ qkt, unsigned short* __restrict__ out)
{
  int b = blockIdx.x, tid = threadIdx.x;
  __shared__ float sq[16][128], sk[16][128], sv[16][128];
  __shared__ float sc[16][4][16];
  for (int i = tid; i < T_*ENC_; i += 128) {
    int tt = i >> 7, j = i & 127;
    long a = ((long)b*T_ + tt)*384;
    sq[tt][j] = bf2f(qkt[a + j]);
    sk[tt][j] = bf2f(qkt[a + 128 + j]);
    sv[tt][j] = bf2f(qkt[a + 256 + j]);
  }
  __syncthreads();
  for (int e = tid; e < 1024; e += 128) {
    int t = e >> 6, s = (e >> 2) & 15, h2 = e & 3;
    float pp = 0.0f;
    #pragma unroll
    for (int d2 = 0; d2 < 32; ++d2) pp += sq[t][h2*32 + d2] * sk[s][h2*32 + d2];
    sc[t][h2][s] = pp * SCALE_;
  }
  __syncthreads();
  if (tid < 64) {
    int t = tid >> 2, h2 = tid & 3;
    float mx = -1e30f;
    for (int s = 0; s < 16; ++s) mx = fmaxf(mx, sc[t][h2][s]);
    float sum = 0.0f;
    for (int s = 0; s < 16; ++s) { float e2 = expf(sc[t][h2][s] - mx); sc[t][h2][s] = e2; sum += e2; }
    float inv = 1.0f / sum;
    for (int s = 0; s < 16; ++s) sc[t][h2][s] *= inv;
  }
  __syncthreads();
  int h2 = tid >> 5, d2 = tid & 31;
  for (int t = 0; t < 16; ++t) {
    float acc = 0.0f;
    for (int s = 0; s < 16; ++s) acc += sc[t][h2][s] * sv[s][h2*32 + d2];
    out[((long)b*T_ + t)*128 + tid] = f2bf(acc);
  }
}

extern "C" void kernel_launch(void* const* d_in, const int* in_sizes, int n_in,
                              void* d_out, int out_size, void* d_ws, size_t ws_size,
                              hipStream_t stream)
{
  const float* hist    = (const float*)d_in[0];
  const float* nbrs    = (const float*)d_in[1];
  const float* va      = (const float*)d_in[2];
  const float* nbrsva  = (const float*)d_in[3];
  const float* cls     = (const float*)d_in[6];
  const float* nbrscls = (const float*)d_in[7];
  const unsigned char* mask = (const unsigned char*)d_in[8];
  const float* W1  = (const float*)d_in[9];
  const float* b1  = (const float*)d_in[10];
  const float* Wih = (const float*)d_in[11];
  const float* Whh = (const float*)d_in[12];
  const float* bih = (const float*)d_in[13];
  const float* bhh = (const float*)d_in[14];
  const float* Wq  = (const float*)d_in[15];
  const float* bq  = (const float*)d_in[16];
  const float* Wk  = (const float*)d_in[17];
  const float* bk  = (const float*)d_in[18];
  const float* Wv  = (const float*)d_in[19];
  const float* bv  = (const float*)d_in[20];
  const float* Wg1a = (const float*)d_in[21];
  const float* bg1a = (const float*)d_in[22];
  const float* Wg1g = (const float*)d_in[23];
  const float* bg1g = (const float*)d_in[24];
  const float* Wqt = (const float*)d_in[25];
  const float* bqt = (const float*)d_in[26];
  const float* Wkt = (const float*)d_in[27];
  const float* bkt = (const float*)d_in[28];
  const float* Wvt = (const float*)d_in[29];
  const float* bvt = (const float*)d_in[30];
  const float* Wg2a = (const float*)d_in[31];
  const float* bg2a = (const float*)d_in[32];
  const float* Wg2g = (const float*)d_in[33];
  const float* bg2g = (const float*)d_in[34];
  const float* ln_g = (const float*)d_in[35];
  const float* ln_b = (const float*)d_in[36];

  // pick largest t-chunk the workspace affords
  size_t fixed = 0;
  {
    size_t items[] = {
      (size_t)GATE*KCAT*2, (size_t)GATE*4, (size_t)2*ENC_*ENC_*2, (size_t)2*ENC_*4,
      (size_t)ENC_*ENC_*2, (size_t)3*ENC_*ENC_*2, (size_t)3*ENC_*4,
      (size_t)2*ENC_*ENC_*2, (size_t)2*ENC_*4, (size_t)2*ENC_*ENC_*2, (size_t)2*ENC_*4,
      (size_t)T_*MROWS*64*2,           // XencB
      (size_t)B_*T_*ENC_*4,            // hh
      (size_t)T_*B_*ENC_*4,            // qbuf
      (size_t)MROWS*ENC_*2,            // Hsp
      (size_t)NBLK3*256*32*4,          // csp
      (size_t)B_*T_*ENC_*2,            // spaB
      (size_t)B_*T_*2*ENC_*4,          // t12
      (size_t)B_*T_*ENC_*4,            // S1
      (size_t)B_*T_*ENC_*2,            // valsB
      (size_t)B_*T_*3*ENC_*2,          // qktB
      (size_t)B_*T_*ENC_*2,            // atoB
      (size_t)B_*G_*4, (size_t)78*4, (size_t)4
    };
    for (size_t v : items) fixed += (v + 255) & ~(size_t)255;
  }
  int tch = 16, ltch = 4;
  while (tch > 2 && fixed + ((size_t)tch*N_*256*2 + 255) > ws_size) { tch >>= 1; ltch--; }

  char* base = (char*)d_ws;
  size_t off = 0;
  auto alloc = [&](size_t bytes) { char* r = base + off; off = (off + bytes + 255) & ~(size_t)255; return r; };
  unsigned short* WcatB = (unsigned short*)alloc(GATE*KCAT*2);
  float*          biasg = (float*)alloc(GATE*4);
  unsigned short* WkvB  = (unsigned short*)alloc(2*ENC_*ENC_*2);
  float*          bkv   = (float*)alloc(2*ENC_*4);
  unsigned short* WqB   = (unsigned short*)alloc(ENC_*ENC_*2);
  unsigned short* WqktB = (unsigned short*)alloc(3*ENC_*ENC_*2);
  float*          bqkt  = (float*)alloc(3*ENC_*4);
  unsigned short* Wg1B  = (unsigned short*)alloc(2*ENC_*ENC_*2);
  float*          bg1   = (float*)alloc(2*ENC_*4);
  unsigned short* Wg2B  = (unsigned short*)alloc(2*ENC_*ENC_*2);
  float*          bg2   = (float*)alloc(2*ENC_*4);
  unsigned short* XencB = (unsigned short*)alloc((size_t)T_*MROWS*64*2);
  float*          hh    = (float*)alloc((size_t)B_*T_*ENC_*4);
  float*          qbuf  = (float*)alloc((size_t)T_*B_*ENC_*4);
  unsigned short* Hsp   = (unsigned short*)alloc((size_t)MROWS*ENC_*2);
  float*          csp   = (float*)alloc((size_t)NBLK3*256*32*4);
  unsigned short* spaB  = (unsigned short*)alloc((size_t)B_*T_*ENC_*2);
  float*          t12   = (float*)alloc((size_t)B_*T_*2*ENC_*4);
  float*          S1    = (float*)alloc((size_t)B_*T_*ENC_*4);
  unsigned short* valsB = (unsigned short*)alloc((size_t)B_*T_*ENC_*2);
  unsigned short* qktB  = (unsigned short*)alloc((size_t)B_*T_*3*ENC_*2);
  unsigned short* atoB  = (unsigned short*)alloc((size_t)B_*T_*ENC_*2);
  int*            nidx  = (int*)alloc((size_t)B_*G_*4);
  int*            bcnt  = (int*)alloc(78*4);
  int*            wsel  = (int*)alloc(4);
  unsigned short* knvB  = (unsigned short*)alloc((size_t)tch*N_*256*2);

  k_prep<<<384, 256, 0, stream>>>(
      Wih, Whh, bih, bhh, Wk, bk, Wv, bv, Wq,
      Wqt, bqt, Wkt, bkt, Wvt, bvt,
      Wg1a, bg1a, Wg1g, bg1g, Wg2a, bg2a, Wg2g, bg2g,
      WcatB, biasg, WkvB, bkv, WqB, WqktB, bqkt, Wg1B, bg1, Wg2B, bg2);
  k_detect<<<1, 256, 0, stream>>>(mask, wsel);
  k_count<<<78, 256, 0, stream>>>(mask, wsel, bcnt);
  k_fill<<<78, 256, 0, stream>>>(mask, wsel, bcnt, nidx);
  k_encode_all<<<dim3(MROWS*64/256, T_), 256, 0, stream>>>(
      hist, cls, va, nbrs, nbrscls, nbrsva, W1, b1, XencB);

  AP ap;
  ap.Xenc = XencB; ap.Wcat = WcatB; ap.Wkv = WkvB; ap.Wq = WqB;
  ap.biasg = biasg; ap.bkv = bkv; ap.bq = bq;
  ap.hh = hh; ap.qbuf = qbuf; ap.knvB = knvB; ap.Hsp = Hsp; ap.csp = csp;
  ap.tch = tch;
  for (int c0 = 0; c0 < T_; c0 += tch) {
    ap.c0 = c0;
    k_lstm<<<NBLK3, 256, 0, stream>>>(ap);
    k_attn_sp<<<(B_*tch)/4, 256, 0, stream>>>(c0, ltch, qbuf, knvB, bk, bv, nidx, spaB);
  }

  // tail
  k_gemm_bf16<<<dim3((B_*T_)/64, 2), 256, 0, stream>>>(spaB, 128, Wg1B, 128, bg1, t12, 256, 128);
  k_glu_addln<<<(B_*T_*64)/256, 256, 0, stream>>>(t12, hh, ln_g, ln_b, S1, valsB, nullptr);
  k_gemm_bf16o<<<dim3((B_*T_)/64, 3), 256, 0, stream>>>(valsB, 128, WqktB, 128, bqkt, qktB, 384, 128);
  k_attn_t<<<B_, 128, 0, stream>>>(qktB, atoB);
  k_gemm_bf16<<<dim3((B_*T_)/64, 2), 256, 0, stream>>>(atoB, 128, Wg2B, 128, bg2, t12, 256, 128);
  k_glu_addln<<<(B_*T_*64)/256, 256, 0, stream>>>(t12, S1, ln_g, ln_b, nullptr, nullptr, (float*)d_out);
}

// Round 11
// 351.677 us; speedup vs baseline: 2.3154x; 2.3154x over previous
//
#include <hip/hip_runtime.h>
#include <math.h>

#define T_ 16
#define B_ 512
#define N_ 8192
#define G_ 39
#define ENC_ 128
#define TH_ 64
#define MROWS 8704          // B_ + N_
#define GATE 512            // 4*ENC_
#define KCAT 192            // TH_ + ENC_
#define SCALE_ 0.08838834764831845f
#define LNEPS 1e-5f
#define NBLK 136            // MROWS/64

typedef short bf16x8 __attribute__((ext_vector_type(8)));
typedef float f32x4  __attribute__((ext_vector_type(4)));

__device__ __forceinline__ float sigm(float x){ return 1.0f/(1.0f+expf(-x)); }
__device__ __forceinline__ float rcpf(float x){ return __builtin_amdgcn_rcpf(x); }
__device__ __forceinline__ float sigm_f(float x){ return rcpf(1.0f + __expf(-x)); }
__device__ __forceinline__ float tanh_f(float x){ return 1.0f - 2.0f*rcpf(__expf(2.0f*x) + 1.0f); }
__device__ __forceinline__ unsigned short f2bf(float f){
  unsigned int u = __float_as_uint(f);
  unsigned int r = u + 0x7FFFu + ((u>>16)&1u);
  return (unsigned short)(r>>16);
}
__device__ __forceinline__ float bf2f(unsigned short h){
  return __uint_as_float(((unsigned int)h)<<16);
}

// ================= prep: convert weights to bf16, build fused/block-diag mats ========
__global__ __launch_bounds__(256) void k_prep(
    const float* __restrict__ Wih, const float* __restrict__ Whh,
    const float* __restrict__ bih, const float* __restrict__ bhh,
    const float* __restrict__ Wk,  const float* __restrict__ Wv,
    const float* __restrict__ Wq,
    const float* __restrict__ Wqt, const float* __restrict__ bqt,
    const float* __restrict__ Wkt, const float* __restrict__ bkt,
    const float* __restrict__ Wvt, const float* __restrict__ bvt,
    const float* __restrict__ Wg1a, const float* __restrict__ bg1a,
    const float* __restrict__ Wg1g, const float* __restrict__ bg1g,
    const float* __restrict__ Wg2a, const float* __restrict__ bg2a,
    const float* __restrict__ Wg2g, const float* __restrict__ bg2g,
    unsigned short* __restrict__ WcatB, float* __restrict__ biasg,
    unsigned short* __restrict__ WqB,
    unsigned short* __restrict__ WkD,  unsigned short* __restrict__ WvD,
    float* __restrict__ zero512,
    unsigned short* __restrict__ WqktB, float* __restrict__ bqkt,
    unsigned short* __restrict__ Wg1B,  float* __restrict__ bg1,
    unsigned short* __restrict__ Wg2B,  float* __restrict__ bg2)
{
  int i = blockIdx.x*256 + threadIdx.x;
  if (i < GATE*KCAT) {
    int n = i / KCAT, k = i % KCAT;
    WcatB[i] = f2bf((k < TH_) ? Wih[n*TH_ + k] : Whh[n*ENC_ + (k - TH_)]);
  }
  if (i < GATE) biasg[i] = bih[i] + bhh[i];
  if (i < ENC_*ENC_) WqB[i] = f2bf(Wq[i]);
  // WkD (512x128): row r = h*128+e, col dc: Wk[dc][e] if dc in head h else 0
  if (i < 512*128) {
    int r = i >> 7, dc = i & 127;
    int h = r >> 7, e = r & 127;
    WkD[i] = ((dc >> 5) == h) ? f2bf(Wk[dc*128 + e]) : (unsigned short)0;
  }
  // WvD (128x512): row r = out channel c, col kk = h'*128+e: Wv[c][e] if h'==c>>5
  if (i < 128*512) {
    int r = i >> 9, kk = i & 511;
    int hp = kk >> 7, e = kk & 127;
    WvD[i] = (hp == (r >> 5)) ? f2bf(Wv[r*128 + e]) : (unsigned short)0;
  }
  if (i < 512) zero512[i] = 0.0f;
  if (i < 2*ENC_*ENC_) {
    int n = i >> 7, k = i & 127;
    Wg1B[i] = f2bf((n < ENC_) ? Wg1a[n*ENC_ + k] : Wg1g[(n-ENC_)*ENC_ + k]);
    Wg2B[i] = f2bf((n < ENC_) ? Wg2a[n*ENC_ + k] : Wg2g[(n-ENC_)*ENC_ + k]);
  }
  if (i < 2*ENC_) {
    bg1[i] = (i < ENC_) ? bg1a[i] : bg1g[i-ENC_];
    bg2[i] = (i < ENC_) ? bg2a[i] : bg2g[i-ENC_];
  }
  if (i < 3*ENC_*ENC_) {
    int n = i >> 7, k = i & 127;
    float w = (n < ENC_) ? Wqt[n*ENC_ + k] : (n < 2*ENC_) ? Wkt[(n-ENC_)*ENC_ + k]
                                                          : Wvt[(n-2*ENC_)*ENC_ + k];
    WqktB[i] = f2bf(w);
  }
  if (i < 3*ENC_) bqkt[i] = (i < ENC_) ? bqt[i] : (i < 2*ENC_) ? bkt[i-ENC_] : bvt[i-2*ENC_];
}

// ================= mask width detect / count / fill (proven) =========================
__device__ __forceinline__ int cellval(const unsigned char* m, long cell, int w) {
  long byte = cell * 128L * w;
  if (w == 1) return m[byte] != 0;
  if (w == 2) return *(const unsigned short*)(m + byte) != 0;
  if (w == 4) return *(const unsigned int*)(m + byte) != 0;
  return *(const unsigned long long*)(m + byte) != 0ULL;
}
__device__ __forceinline__ int cellconsist(const unsigned char* m, long cell, int w) {
  long byte = cell * 128L * w;
  if (w == 1) { unsigned char v = m[byte];
    for (int j = 1; j < 8; ++j) if (m[byte + j] != v) return 0; return 1; }
  if (w == 2) { unsigned short v = *(const unsigned short*)(m + byte);
    for (int j = 1; j < 8; ++j) if (*(const unsigned short*)(m + byte + 2L*j) != v) return 0; return 1; }
  if (w == 4) { unsigned int v = *(const unsigned int*)(m + byte);
    for (int j = 1; j < 8; ++j) if (*(const unsigned int*)(m + byte + 4L*j) != v) return 0; return 1; }
  unsigned long long v = *(const unsigned long long*)(m + byte);
  for (int j = 1; j < 8; ++j) if (*(const unsigned long long*)(m + byte + 8L*j) != v) return 0; return 1;
}

__global__ void k_detect(const unsigned char* __restrict__ mask, int* __restrict__ wsel)
{
  __shared__ int bad;
  int tid = threadIdx.x;
  int chosen = 0;
  for (int w = 1; w <= 8 && !chosen; w <<= 1) {
    if (tid == 0) bad = 0;
    __syncthreads();
    int ok = 1;
    for (int c = tid; c < 512; c += 256) ok &= cellconsist(mask, c, w);
    if (!ok) bad = 1;
    __syncthreads();
    if (!bad) chosen = w;
    __syncthreads();
  }
  if (tid == 0) *wsel = chosen ? chosen : 1;
}

__global__ void k_count(const unsigned char* __restrict__ mask,
                        const int* __restrict__ wsel, int* __restrict__ bcnt)
{
  __shared__ int sc[256];
  int tid = threadIdx.x;
  long cell = (long)blockIdx.x*256 + tid;
  sc[tid] = cellval(mask, cell, *wsel);
  __syncthreads();
  for (int off = 128; off; off >>= 1) {
    if (tid < off) sc[tid] += sc[tid + off];
    __syncthreads();
  }
  if (tid == 0) bcnt[blockIdx.x] = sc[0];
}

__global__ void k_fill(const unsigned char* __restrict__ mask,
                       const int* __restrict__ wsel, const int* __restrict__ bcnt,
                       int* __restrict__ nidx)
{
  __shared__ int sc[256];
  int tid = threadIdx.x, blk = blockIdx.x;
  long cell = (long)blk*256 + tid;
  int on = cellval(mask, cell, *wsel);
  sc[tid] = on;
  __syncthreads();
  for (int off = 1; off < 256; off <<= 1) {
    int v = (tid >= off) ? sc[tid - off] : 0;
    __syncthreads();
    sc[tid] += v;
    __syncthreads();
  }
  int base = 0;
  for (int i = 0; i < blk; ++i) base += bcnt[i];
  nidx[cell] = on ? (base + sc[tid] - 1) : -1;
}

// ================= encode ALL t: elu(in5 @ W1^T + b1) -> XencB[t][m][64] bf16 =========
__global__ __launch_bounds__(256) void k_encode_all(
    const float* __restrict__ hist, const float* __restrict__ cls, const float* __restrict__ va,
    const float* __restrict__ nbrs, const float* __restrict__ nbrscls, const float* __restrict__ nbrsva,
    const float* __restrict__ W1, const float* __restrict__ b1,
    unsigned short* __restrict__ XencB)
{
  int i = blockIdx.x*256 + threadIdx.x;      // over MROWS*64
  int t = blockIdx.y;
  int o = i & 63, m = i >> 6;
  float in0, in1, in2, in3, in4;
  if (m < B_) {
    int r = t*B_ + m;
    in0 = hist[r*2]; in1 = hist[r*2+1]; in2 = cls[r]; in3 = va[r*2]; in4 = va[r*2+1];
  } else {
    int r = t*N_ + (m - B_);
    in0 = nbrs[r*2]; in1 = nbrs[r*2+1]; in2 = nbrscls[r]; in3 = nbrsva[r*2]; in4 = nbrsva[r*2+1];
  }
  const float* w = W1 + o*5;
  float s = b1[o] + in0*w[0] + in1*w[1] + in2*w[2] + in3*w[3] + in4*w[4];
  XencB[((long)t*MROWS + m)*64 + o] = f2bf((s > 0.0f) ? s : expm1f(s));
}

// ================= kernel A: LSTM (R6 structure), no kv; coalesced Hn writeout =======
struct AP {
  const unsigned short *Xenc, *Wcat, *Wq;
  const float *biasg, *bq;
  float *hh;                 // (B,T,128) f32
  unsigned short *qB;        // (T,B,128) bf16
  unsigned short *HnB;       // (T,N,128) bf16
};

// 136 blocks x 64 rows; 512 threads = 8 waves; wave w owns gate-channels w*16..+16
// (all 4 gates). H-part gate weights pinned in regs. ONE barrier per t.
__global__ __launch_bounds__(512, 1) void k_lstm(AP p)
{
  __shared__ unsigned short Hl[2*64*128];    // 32 KB, double-buffered, XOR-swizzled

  const int tid = threadIdx.x;
  const int w = tid >> 6, l = tid & 63;
  const int lr = l & 15, lk = (l >> 4) * 8, lq = (l >> 4) * 4;
  const int bi = blockIdx.x, bm = bi * 64;
  const bool ish = (bi < 8);

  // H-part gate weights pinned: 4 gates x 4 ks
  bf16x8 wgh[4][4];
  #pragma unroll
  for (int g = 0; g < 4; ++g)
    #pragma unroll
    for (int ks = 0; ks < 4; ++ks)
      wgh[g][ks] = *(const bf16x8*)(p.Wcat + (long)(g*128 + w*16 + lr)*KCAT + 64 + ks*32 + lk);

  const int ch = w*16 + lr;
  const float bgi = p.biasg[ch], bgf = p.biasg[128+ch],
              bgg = p.biasg[256+ch], bgo = p.biasg[384+ch];
  const float bqv = ish ? p.bq[ch] : 0.0f;

  for (int i = tid; i < 64*128; i += 512) Hl[i] = 0;   // H(0) buffer 0
  float creg[4][4];
  #pragma unroll
  for (int mi = 0; mi < 4; ++mi)
    #pragma unroll
    for (int q = 0; q < 4; ++q) creg[mi][q] = 0.0f;
  __syncthreads();

  int cur = 0;
  for (int t = 0; t < T_; ++t) {
    // ---- gate GEMM: 96 MFMA/wave ----
    f32x4 acc[4][4] = {};     // [gate][mi]
    #pragma unroll
    for (int ks = 0; ks < 2; ++ks) {          // K 0..63 from Xenc (global, L3-hot)
      bf16x8 a[4];
      #pragma unroll
      for (int mi = 0; mi < 4; ++mi)
        a[mi] = *(const bf16x8*)(p.Xenc + ((long)t*MROWS + bm + mi*16 + lr)*64 + ks*32 + lk);
      #pragma unroll
      for (int g = 0; g < 4; ++g) {
        bf16x8 b = *(const bf16x8*)(p.Wcat + (long)(g*128 + w*16 + lr)*KCAT + ks*32 + lk);
        #pragma unroll
        for (int mi = 0; mi < 4; ++mi)
          acc[g][mi] = __builtin_amdgcn_mfma_f32_16x16x32_bf16(a[mi], b, acc[g][mi], 0, 0, 0);
      }
    }
    #pragma unroll
    for (int ks = 0; ks < 4; ++ks) {          // K 64..191 from Hl[cur]
      bf16x8 a[4];
      #pragma unroll
      for (int mi = 0; mi < 4; ++mi) {
        int row = mi*16 + lr;
        int col = (ks*32 + lk) ^ ((row & 7) << 3);
        a[mi] = *(const bf16x8*)(Hl + cur*8192 + row*128 + col);
      }
      #pragma unroll
      for (int g = 0; g < 4; ++g)
        #pragma unroll
        for (int mi = 0; mi < 4; ++mi)
          acc[g][mi] = __builtin_amdgcn_mfma_f32_16x16x32_bf16(a[mi], wgh[g][ks], acc[g][mi], 0, 0, 0);
    }
    // ---- lane-local cell update (c in registers) ----
    int nxt = cur ^ 1;
    #pragma unroll
    for (int mi = 0; mi < 4; ++mi)
      #pragma unroll
      for (int q = 0; q < 4; ++q) {
        int row = mi*16 + lq + q;
        float gi = acc[0][mi][q] + bgi;
        float gf = acc[1][mi][q] + bgf;
        float gg = acc[2][mi][q] + bgg;
        float go = acc[3][mi][q] + bgo;
        float cc = sigm_f(gf)*creg[mi][q] + sigm_f(gi)*tanh_f(gg);
        creg[mi][q] = cc;
        float hv = sigm_f(go)*tanh_f(cc);
        Hl[nxt*8192 + row*128 + (ch ^ ((row & 7) << 3))] = f2bf(hv);
        if (ish) p.hh[((long)(bm + row)*T_ + t)*128 + ch] = hv;
      }
    __syncthreads();                      // the only per-t barrier
    cur = nxt;
    if (ish) {
      // ---- q projection from new H ----
      f32x4 a2[4] = {};
      #pragma unroll
      for (int ks = 0; ks < 4; ++ks) {
        bf16x8 b = *(const bf16x8*)(p.Wq + (long)(w*16 + lr)*128 + ks*32 + lk);
        #pragma unroll
        for (int mi = 0; mi < 4; ++mi) {
          int row = mi*16 + lr;
          int col = (ks*32 + lk) ^ ((row & 7) << 3);
          bf16x8 a = *(const bf16x8*)(Hl + cur*8192 + row*128 + col);
          a2[mi] = __builtin_amdgcn_mfma_f32_16x16x32_bf16(a, b, a2[mi], 0, 0, 0);
        }
      }
      #pragma unroll
      for (int mi = 0; mi < 4; ++mi)
        #pragma unroll
        for (int q = 0; q < 4; ++q)
          p.qB[((long)t*B_ + bm + mi*16 + lq + q)*128 + ch] = f2bf(a2[mi][q] + bqv);
    } else {
      // ---- staged, coalesced copy of new H -> HnB: 64 rows x 16 chunks of 16B ----
      for (int e = tid; e < 64*16; e += 512) {
        int r = e >> 4, j = e & 15;
        int src = cur*8192 + r*128 + ((j*8) ^ ((r & 7) << 3));
        *(bf16x8*)(p.HnB + ((long)t*N_ + (bm - B_) + r)*128 + j*8) =
            *(const bf16x8*)(Hl + src);
      }
    }
  }
}

// ================= kernel B: spatial attention via qW/hbar (no kv) ===================
// one block of 128 threads per (b,t); h = tid>>5 (head), d = tid&31
__global__ __launch_bounds__(128) void k_attn2(
    const unsigned short* __restrict__ qB,    // (T,B,128)
    const unsigned short* __restrict__ qWB,   // (T*B, 512) = per-head qW
    const unsigned short* __restrict__ HnB,   // (T,N,128)
    const float* __restrict__ bk,
    const int* __restrict__ nidx,
    unsigned short* __restrict__ hbarB)       // (B*T, 512)
{
  __shared__ int sn[G_];
  __shared__ unsigned short hL[G_*128];
  __shared__ float sgh[G_][4];
  int blk = blockIdx.x;
  int b = blk >> 4, t = blk & 15;
  int tid = threadIdx.x;
  int h = tid >> 5, d = tid & 31;
  if (tid < G_) sn[tid] = nidx[b*G_ + tid];
  __syncthreads();
  // gather neighbor h rows (256B each, coalesced across 128 threads)
  for (int g = 0; g < G_; ++g) {
    int ni = sn[g];
    if (ni >= 0) hL[g*128 + tid] = HnB[((long)t*N_ + ni)*128 + tid];
  }
  // q element, qbk_h = q_h . bk_h  (32-lane xor reduce)
  float qel = bf2f(qB[((long)t*B_ + b)*128 + tid]);
  float qbk = qel * bk[tid];
  #pragma unroll
  for (int off = 16; off; off >>= 1) qbk += __shfl_xor(qbk, off);
  // qW fragment: this thread's 4 k-slots for its head
  float qw[4];
  #pragma unroll
  for (int j = 0; j < 4; ++j)
    qw[j] = bf2f(qWB[((long)t*B_ + b)*512 + h*128 + d + j*32]);
  __syncthreads();
  // scores s[g][h] = (h_g . qW_h + qbk_h) * SCALE ; empty cell: qbk_h * SCALE
  for (int g = 0; g < G_; ++g) {
    float s;
    if (sn[g] >= 0) {
      float part = 0.0f;
      #pragma unroll
      for (int j = 0; j < 4; ++j) part += bf2f(hL[g*128 + d + j*32]) * qw[j];
      #pragma unroll
      for (int off = 16; off; off >>= 1) part += __shfl_xor(part, off);
      s = (part + qbk) * SCALE_;
    } else {
      s = qbk * SCALE_;
    }
    if (d == 0) sgh[g][h] = s;   // read back only by this wave's h-group
  }
  // softmax + hbar (per-thread over its 4 k-slots)
  float mx = -1e30f;
  for (int g = 0; g < G_; ++g) mx = fmaxf(mx, sgh[g][h]);
  float den = 0.0f;
  float hb[4] = {0.0f, 0.0f, 0.0f, 0.0f};
  for (int g = 0; g < G_; ++g) {
    float e = expf(sgh[g][h] - mx);
    den += e;
    if (sn[g] >= 0) {
      #pragma unroll
      for (int j = 0; j < 4; ++j) hb[j] += e * bf2f(hL[g*128 + d + j*32]);
    }
  }
  float inv = 1.0f / den;
  #pragma unroll
  for (int j = 0; j < 4; ++j)
    hbarB[((long)b*T_ + t)*512 + h*128 + d + j*32] = f2bf(hb[j] * inv);
}

// ================= bf16 MFMA GEMM: C f32 out =========================================
__global__ __launch_bounds__(256) void k_gemm_bf16(
    const unsigned short* __restrict__ A, int lda,
    const unsigned short* __restrict__ W, int ldw,
    const float* __restrict__ bias,
    float* __restrict__ C, int ldc, int K)
{
  int tid = threadIdx.x;
  int w = tid >> 6, l = tid & 63;
  int lr = l & 15, lk = (l >> 4) * 8, lq = (l >> 4) * 4;
  int bm = blockIdx.x * 64;
  int bn = blockIdx.y * 128 + w * 32;
  f32x4 acc[4][2] = {};
  for (int k0 = 0; k0 < K; k0 += 32) {
    bf16x8 a[4], b[2];
    #pragma unroll
    for (int mi = 0; mi < 4; ++mi)
      a[mi] = *(const bf16x8*)(A + (long)(bm + mi*16 + lr)*lda + k0 + lk);
    #pragma unroll
    for (int ni = 0; ni < 2; ++ni)
      b[ni] = *(const bf16x8*)(W + (long)(bn + ni*16 + lr)*ldw + k0 + lk);
    #pragma unroll
    for (int mi = 0; mi < 4; ++mi)
      #pragma unroll
      for (int ni = 0; ni < 2; ++ni)
        acc[mi][ni] = __builtin_amdgcn_mfma_f32_16x16x32_bf16(a[mi], b[ni], acc[mi][ni], 0, 0, 0);
  }
  #pragma unroll
  for (int mi = 0; mi < 4; ++mi)
    #pragma unroll
    for (int ni = 0; ni < 2; ++ni) {
      int col = bn + ni*16 + lr;
      float bb = bias[col];
      #pragma unroll
      for (int q = 0; q < 4; ++q)
        C[(long)(bm + mi*16 + lq + q)*ldc + col] = acc[mi][ni][q] + bb;
    }
}

// same but bf16 output
__global__ __launch_bounds__(256) void k_gemm_bf16o(
    const unsigned short* __restrict__ A, int lda,
    const unsigned short* __restrict__ W, int ldw,
    const float* __restrict__ bias,
    unsigned short* __restrict__ C, int ldc, int K)
{
  int tid = threadIdx.x;
  int w = tid >> 6, l = tid & 63;
  int lr = l & 15, lk = (l >> 4) * 8, lq = (l >> 4) * 4;
  int bm = blockIdx.x * 64;
  int bn = blockIdx.y * 128 + w * 32;
  f32x4 acc[4][2] = {};
  for (int k0 = 0; k0 < K; k0 += 32) {
    bf16x8 a[4], b[2];
    #pragma unroll
    for (int mi = 0; mi < 4; ++mi)
      a[mi] = *(const bf16x8*)(A + (long)(bm + mi*16 + lr)*lda + k0 + lk);
    #pragma unroll
    for (int ni = 0; ni < 2; ++ni)
      b[ni] = *(const bf16x8*)(W + (long)(bn + ni*16 + lr)*ldw + k0 + lk);
    #pragma unroll
    for (int mi = 0; mi < 4; ++mi)
      #pragma unroll
      for (int ni = 0; ni < 2; ++ni)
        acc[mi][ni] = __builtin_amdgcn_mfma_f32_16x16x32_bf16(a[mi], b[ni], acc[mi][ni], 0, 0, 0);
  }
  #pragma unroll
  for (int mi = 0; mi < 4; ++mi)
    #pragma unroll
    for (int ni = 0; ni < 2; ++ni) {
      int col = bn + ni*16 + lr;
      float bb = bias[col];
      #pragma unroll
      for (int q = 0; q < 4; ++q)
        C[(long)(bm + mi*16 + lq + q)*ldc + col] = f2bf(acc[mi][ni][q] + bb);
    }
}

// ================= fused glu + residual add + layernorm ==============================
__global__ __launch_bounds__(256) void k_glu_addln(
    const float* __restrict__ t12, const float* __restrict__ res,
    const float* __restrict__ lg, const float* __restrict__ lb,
    float* __restrict__ sum_out, unsigned short* __restrict__ ln_bf16,
    float* __restrict__ ln_f32)
{
  int gtid = blockIdx.x*256 + threadIdx.x;
  int r = gtid >> 6;
  int l = threadIdx.x & 63;
  if (r >= B_*T_) return;
  long b4 = (long)r*256, b2 = (long)r*128;
  float xA = res[b2 + l]      + t12[b4 + l]      * sigm(t12[b4 + 128 + l]);
  float xB = res[b2 + 64 + l] + t12[b4 + 64 + l] * sigm(t12[b4 + 192 + l]);
  if (sum_out) { sum_out[b2 + l] = xA; sum_out[b2 + 64 + l] = xB; }
  float s = xA + xB, s2 = xA*xA + xB*xB;
  #pragma unroll
  for (int off = 32; off; off >>= 1) { s += __shfl_xor(s, off); s2 += __shfl_xor(s2, off); }
  float mean = s * (1.0f/128.0f);
  float var  = s2 * (1.0f/128.0f) - mean*mean;
  float inv  = rsqrtf(var + LNEPS);
  float oA = (xA - mean)*inv*lg[l]      + lb[l];
  float oB = (xB - mean)*inv*lg[64 + l] + lb[64 + l];
  if (ln_bf16) { ln_bf16[b2 + l] = f2bf(oA); ln_bf16[b2 + 64 + l] = f2bf(oB); }
  if (ln_f32)  { ln_f32[b2 + l] = oA;        ln_f32[b2 + 64 + l] = oB; }
}

// ================= temporal attention (bf16 qkt input) ===============================
__global__ __launch_bounds__(128) void k_attn_t(
    const unsigned short* __restrict__ qkt, unsigned short* __restrict__ out)
{
  int b = blockIdx.x, tid = threadIdx.x;
  __shared__ float sq[16][128], sk[16][128], sv[16][128];
  __shared__ float sc[16][4][16];
  for (int i = tid; i < T_*ENC_; i += 128) {
    int tt = i >> 7, j = i & 127;
    long a = ((long)b*T_ + tt)*384;
    sq[tt][j] = bf2f(qkt[a + j]);
    sk[tt][j] = bf2f(qkt[a + 128 + j]);
    sv[tt][j] = bf2f(qkt[a + 256 + j]);
  }
  __syncthreads();
  for (int e = tid; e < 1024; e += 128) {
    int t = e >> 6, s = (e >> 2) & 15, h2 = e & 3;
    float pp = 0.0f;
    #pragma unroll
    for (int d2 = 0; d2 < 32; ++d2) pp += sq[t][h2*32 + d2] * sk[s][h2*32 + d2];
    sc[t][h2][s] = pp * SCALE_;
  }
  __syncthreads();
  if (tid < 64) {
    int t = tid >> 2, h2 = tid & 3;
    float mx = -1e30f;
    for (int s = 0; s < 16; ++s) mx = fmaxf(mx, sc[t][h2][s]);
    float sum = 0.0f;
    for (int s = 0; s < 16; ++s) { float e2 = expf(sc[t][h2][s] - mx); sc[t][h2][s] = e2; sum += e2; }
    float inv = 1.0f / sum;
    for (int s = 0; s < 16; ++s) sc[t][h2][s] *= inv;
  }
  __syncthreads();
  int h2 = tid >> 5, d2 = tid & 31;
  for (int t = 0; t < 16; ++t) {
    float acc = 0.0f;
    for (int s = 0; s < 16; ++s) acc += sc[t][h2][s] * sv[s][h2*32 + d2];
    out[((long)b*T_ + t)*128 + tid] = f2bf(acc);
  }
}

extern "C" void kernel_launch(void* const* d_in, const int* in_sizes, int n_in,
                              void* d_out, int out_size, void* d_ws, size_t ws_size,
                              hipStream_t stream)
{
  const float* hist    = (const float*)d_in[0];
  const float* nbrs    = (const float*)d_in[1];
  const float* va      = (const float*)d_in[2];
  const float* nbrsva  = (const float*)d_in[3];
  const float* cls     = (const float*)d_in[6];
  const float* nbrscls = (const float*)d_in[7];
  const unsigned char* mask = (const unsigned char*)d_in[8];
  const float* W1  = (const float*)d_in[9];
  const float* b1  = (const float*)d_in[10];
  const float* Wih = (const float*)d_in[11];
  const float* Whh = (const float*)d_in[12];
  const float* bih = (const float*)d_in[13];
  const float* bhh = (const float*)d_in[14];
  const float* Wq  = (const float*)d_in[15];
  const float* bq  = (const float*)d_in[16];
  const float* Wk  = (const float*)d_in[17];
  const float* bk  = (const float*)d_in[18];
  const float* Wv  = (const float*)d_in[19];
  const float* bv  = (const float*)d_in[20];
  const float* Wg1a = (const float*)d_in[21];
  const float* bg1a = (const float*)d_in[22];
  const float* Wg1g = (const float*)d_in[23];
  const float* bg1g = (const float*)d_in[24];
  const float* Wqt = (const float*)d_in[25];
  const float* bqt = (const float*)d_in[26];
  const float* Wkt = (const float*)d_in[27];
  const float* bkt = (const float*)d_in[28];
  const float* Wvt = (const float*)d_in[29];
  const float* bvt = (const float*)d_in[30];
  const float* Wg2a = (const float*)d_in[31];
  const float* bg2a = (const float*)d_in[32];
  const float* Wg2g = (const float*)d_in[33];
  const float* bg2g = (const float*)d_in[34];
  const float* ln_g = (const float*)d_in[35];
  const float* ln_b = (const float*)d_in[36];

  char* base = (char*)d_ws;
  size_t off = 0;
  auto alloc = [&](size_t bytes) { char* r = base + off; off = (off + bytes + 255) & ~(size_t)255; return r; };
  unsigned short* WcatB = (unsigned short*)alloc(GATE*KCAT*2);
  float*          biasg = (float*)alloc(GATE*4);
  unsigned short* WqB   = (unsigned short*)alloc(ENC_*ENC_*2);
  unsigned short* WkD   = (unsigned short*)alloc(512*128*2);
  unsigned short* WvD   = (unsigned short*)alloc(128*512*2);
  float*          zero512 = (float*)alloc(512*4);
  unsigned short* WqktB = (unsigned short*)alloc(3*ENC_*ENC_*2);
  float*          bqkt  = (float*)alloc(3*ENC_*4);
  unsigned short* Wg1B  = (unsigned short*)alloc(2*ENC_*ENC_*2);
  float*          bg1   = (float*)alloc(2*ENC_*4);
  unsigned short* Wg2B  = (unsigned short*)alloc(2*ENC_*ENC_*2);
  float*          bg2   = (float*)alloc(2*ENC_*4);
  unsigned short* XencB = (unsigned short*)alloc((size_t)T_*MROWS*64*2);
  float*          hh    = (float*)alloc((size_t)B_*T_*ENC_*4);
  unsigned short* qB    = (unsigned short*)alloc((size_t)T_*B_*ENC_*2);
  unsigned short* HnB   = (unsigned short*)alloc((size_t)T_*N_*ENC_*2);
  unsigned short* qWB   = (unsigned short*)alloc((size_t)T_*B_*512*2);
  unsigned short* hbarB = (unsigned short*)alloc((size_t)B_*T_*512*2);
  unsigned short* spaB  = (unsigned short*)alloc((size_t)B_*T_*ENC_*2);
  float*          t12   = (float*)alloc((size_t)B_*T_*2*ENC_*4);
  float*          S1    = (float*)alloc((size_t)B_*T_*ENC_*4);
  unsigned short* valsB = (unsigned short*)alloc((size_t)B_*T_*ENC_*2);
  unsigned short* qktB  = (unsigned short*)alloc((size_t)B_*T_*3*ENC_*2);
  unsigned short* atoB  = (unsigned short*)alloc((size_t)B_*T_*ENC_*2);
  int*            nidx  = (int*)alloc((size_t)B_*G_*4);
  int*            bcnt  = (int*)alloc(78*4);
  int*            wsel  = (int*)alloc(4);

  const int ROWS = B_*T_;                    // 8192

  k_prep<<<384, 256, 0, stream>>>(
      Wih, Whh, bih, bhh, Wk, Wv, Wq,
      Wqt, bqt, Wkt, bkt, Wvt, bvt,
      Wg1a, bg1a, Wg1g, bg1g, Wg2a, bg2a, Wg2g, bg2g,
      WcatB, biasg, WqB, WkD, WvD, zero512, WqktB, bqkt, Wg1B, bg1, Wg2B, bg2);
  k_detect<<<1, 256, 0, stream>>>(mask, wsel);
  k_count<<<78, 256, 0, stream>>>(mask, wsel, bcnt);
  k_fill<<<78, 256, 0, stream>>>(mask, wsel, bcnt, nidx);
  k_encode_all<<<dim3(MROWS*64/256, T_), 256, 0, stream>>>(
      hist, cls, va, nbrs, nbrscls, nbrsva, W1, b1, XencB);

  AP ap;
  ap.Xenc = XencB; ap.Wcat = WcatB; ap.Wq = WqB;
  ap.biasg = biasg; ap.bq = bq;
  ap.hh = hh; ap.qB = qB; ap.HnB = HnB;
  k_lstm<<<NBLK, 512, 0, stream>>>(ap);

  // qW = q @ WkD^T  (M=8192, N=512, K=128)
  k_gemm_bf16o<<<dim3(ROWS/64, 4), 256, 0, stream>>>(qB, 128, WkD, 128, zero512, qWB, 512, 128);
  // spatial attention -> hbar
  k_attn2<<<ROWS, 128, 0, stream>>>(qB, qWB, HnB, bk, nidx, hbarB);
  // spa = hbar @ WvD^T + bv  (M=8192, N=128, K=512)
  k_gemm_bf16o<<<dim3(ROWS/64, 1), 256, 0, stream>>>(hbarB, 512, WvD, 512, bv, spaB, 128, 512);

  // tail
  k_gemm_bf16<<<dim3(ROWS/64, 2), 256, 0, stream>>>(spaB, 128, Wg1B, 128, bg1, t12, 256, 128);
  k_glu_addln<<<(ROWS*64)/256, 256, 0, stream>>>(t12, hh, ln_g, ln_b, S1, valsB, nullptr);
  k_gemm_bf16o<<<dim3(ROWS/64, 3), 256, 0, stream>>>(valsB, 128, WqktB, 128, bqkt, qktB, 384, 128);
  k_attn_t<<<B_, 128, 0, stream>>>(qktB, atoB);
  k_gemm_bf16<<<dim3(ROWS/64, 2), 256, 0, stream>>>(atoB, 128, Wg2B, 128, bg2, t12, 256, 128);
  k_glu_addln<<<(ROWS*64)/256, 256, 0, stream>>>(t12, S1, ln_g, ln_b, nullptr, nullptr, (float*)d_out);
}